// Round 25
// baseline (55.950 us; speedup 1.0000x reference)
//
#include <hip/hip_runtime.h>
#include <hip/hip_bf16.h>

typedef float  f32x4  __attribute__((ext_vector_type(4)));
typedef float  f32x8  __attribute__((ext_vector_type(8)));
typedef float  f32x16 __attribute__((ext_vector_type(16)));
typedef short  s4v    __attribute__((ext_vector_type(4)));
typedef short  s8v    __attribute__((ext_vector_type(8)));
typedef __bf16 b4v    __attribute__((ext_vector_type(4)));
typedef __bf16 b8v    __attribute__((ext_vector_type(8)));
typedef unsigned int u32;
typedef unsigned short ushort;

#define T_DIM  2048
#define C_DIM  1024

// ---------- helpers ----------

typedef const __attribute__((address_space(1))) u32 gu32;
typedef __attribute__((address_space(3))) u32 lu32;

static __device__ __forceinline__ void glds16(const void* g, void* l) {
  __builtin_amdgcn_global_load_lds((gu32*)g, (lu32*)l, 16, 0, 0);
}

static __device__ __forceinline__ b8v ldb8(const ushort* p) {
  return __builtin_bit_cast(b8v, *reinterpret_cast<const s8v*>(p));
}

static __device__ __forceinline__ b4v cvt4(f32x4 v) {
  b4v r;
#pragma unroll
  for (int i = 0; i < 4; ++i) r[i] = (__bf16)v[i];
  return r;
}

static __device__ __forceinline__ ushort bfu(float f) {
  __bf16 h = (__bf16)f;
  return __builtin_bit_cast(ushort, h);
}

static __device__ __forceinline__ float b2f(ushort u) {
  u32 x = ((u32)u) << 16;
  return __builtin_bit_cast(float, x);
}

static __device__ __forceinline__ f32x16 mfma32(b8v a, b8v b, f32x16 c) {
  return __builtin_amdgcn_mfma_f32_32x32x16_bf16(a, b, c, 0, 0, 0);
}

#define BAR_VM(N)                                                        \
  asm volatile("s_waitcnt vmcnt(" #N ") lgkmcnt(0)" ::: "memory");       \
  __builtin_amdgcn_s_barrier();                                          \
  asm volatile("" ::: "memory");

// ---------- kernel 0: W -> Wt bf16 transposed [3][128][1024] ----------
__global__ __launch_bounds__(256) void wconv(const float* __restrict__ Wq,
                                             const float* __restrict__ Wk,
                                             const float* __restrict__ Wv,
                                             ushort* __restrict__ Wt) {
  __shared__ float lds[32][65];
  const int m  = blockIdx.z;
  const int c0 = blockIdx.x * 32;
  const int h0 = blockIdx.y * 64;
  const float* W = (m == 0) ? Wq : (m == 1) ? Wk : Wv;

  const int cl = threadIdx.x >> 3;
  const int h8 = (threadIdx.x & 7) * 8;
  {
    float4 a = *reinterpret_cast<const float4*>(W + (c0 + cl) * 128 + h0 + h8);
    float4 b =
        *reinterpret_cast<const float4*>(W + (c0 + cl) * 128 + h0 + h8 + 4);
    lds[cl][h8] = a.x; lds[cl][h8 + 1] = a.y;
    lds[cl][h8 + 2] = a.z; lds[cl][h8 + 3] = a.w;
    lds[cl][h8 + 4] = b.x; lds[cl][h8 + 5] = b.y;
    lds[cl][h8 + 6] = b.z; lds[cl][h8 + 7] = b.w;
  }
  __syncthreads();
  const int hl = threadIdx.x >> 2;
  const int cs = (threadIdx.x & 3) * 8;
  s8v o;
#pragma unroll
  for (int i = 0; i < 8; ++i) o[i] = (short)bfu(lds[cs + i][hl]);
  *reinterpret_cast<s8v*>(Wt + (m * 128 + h0 + hl) * C_DIM + c0 + cs) = o;
}

// ---------- kernel 1: q/k/v projection (verified round-22/24 version) ----------
__global__ __launch_bounds__(512) void proj(const float* __restrict__ x,
                                            const ushort* __restrict__ Wt,
                                            ushort* __restrict__ q,
                                            ushort* __restrict__ k,
                                            ushort* __restrict__ vt) {
  __shared__ __align__(16) ushort Ab[2][32 * 72];
  __shared__ __align__(16) ushort Bb[2][128 * 64];
  float* red = (float*)&Bb[0][0];
  ushort* stage = &Bb[1][0];

  const int t   = threadIdx.x;
  const int w   = t >> 6;
  const int lid = t & 63;
  const int hi  = lid >> 5;
  const int ln  = lid & 31;
  const int ks  = w >> 2;
  const int nc  = w & 3;
  const int m   = blockIdx.y;
  const int r0  = blockIdx.x * 32;

  const int arow = t >> 4;
  const int acol = (t & 15) * 4;
  const float* ag = x + (r0 + arow) * C_DIM + acol;

  const int bswz = (((lid & 7) ^ (lid >> 3)) << 4);
  const char* bg = (const char*)(Wt + m * 128 * C_DIM);

  f32x16 acc[2] = {};

#define PROJ_BSTAGE(KK, BUF)                                              \
  _Pragma("unroll") for (int j = 0; j < 2; ++j) {                         \
    int h = j * 64 + w * 8 + (lid >> 3);                                  \
    glds16(bg + h * 2048 + (KK) * 2 + bswz,                               \
           (char*)&Bb[BUF][0] + j * 8192 + w * 1024);                     \
  }

  f32x4 av = *reinterpret_cast<const f32x4*>(ag);
  PROJ_BSTAGE(0, 0)
  {
    b4v ac = cvt4(av);
    *reinterpret_cast<s4v*>(&Ab[0][arow * 72 + acol]) =
        __builtin_bit_cast(s4v, ac);
  }
  __syncthreads();

  int cur = 0;
#pragma unroll 1
  for (int i = 0; i < 16; ++i) {
    const int nxt = cur ^ 1;
    f32x4 an;
    if (i < 15) {
      const int kk = (i + 1) * 64;
      PROJ_BSTAGE(kk, nxt)
      an = *reinterpret_cast<const f32x4*>(ag + kk);
    }

    const int h = nc * 32 + ln;
#pragma unroll
    for (int c = 0; c < 2; ++c) {
      const int s = ks * 2 + c;
      b8v af = ldb8(&Ab[cur][ln * 72 + s * 16 + hi * 8]);
      int inner = ((s * 2 + hi) << 4) ^ ((h & 7) << 4);
      b8v bf =
          ldb8((const ushort*)((const char*)&Bb[cur][0] + h * 128 + inner));
      __builtin_amdgcn_s_setprio(1);
      acc[c] = mfma32(af, bf, acc[c]);
      __builtin_amdgcn_s_setprio(0);
    }

    if (i < 15) {
      b4v anc = cvt4(an);
      *reinterpret_cast<s4v*>(&Ab[nxt][arow * 72 + acol]) =
          __builtin_bit_cast(s4v, anc);
    }
    __syncthreads();
    cur = nxt;
  }
#undef PROJ_BSTAGE

  f32x16 fa = acc[0] + acc[1];

  if (ks == 1) {
#pragma unroll
    for (int r = 0; r < 16; ++r) {
      int qm = (r & 3) + 8 * (r >> 2) + 4 * hi;
      red[(nc * 32 + qm) * 32 + ln] = fa[r];
    }
  }
  __syncthreads();
  if (ks == 0) {
#pragma unroll
    for (int r = 0; r < 16; ++r) {
      int qm = (r & 3) + 8 * (r >> 2) + 4 * hi;
      fa[r] += red[(nc * 32 + qm) * 32 + ln];
    }
    if (m < 2) {
#pragma unroll
      for (int r = 0; r < 16; ++r) {
        int row = (r & 3) + 8 * (r >> 2) + 4 * hi;
        stage[row * 136 + nc * 32 + ln] = bfu(fa[r]);
      }
    } else {
#pragma unroll
      for (int r = 0; r < 16; ++r) {
        int trow = (r & 3) + 8 * (r >> 2) + 4 * hi;
        stage[(nc * 32 + ln) * 40 + trow] = bfu(fa[r]);
      }
    }
  }
  __syncthreads();

  if (m < 2) {
    ushort* dst = (m == 0) ? q : k;
    int row = t >> 4, col8 = t & 15;
    s8v v8 = *reinterpret_cast<const s8v*>(&stage[row * 136 + col8 * 8]);
    *reinterpret_cast<s8v*>(&dst[(r0 + row) * 128 + col8 * 8]) = v8;
  } else {
    int b = blockIdx.x >> 6;
    int tbase = (blockIdx.x & 63) * 32;
    int h2 = t >> 2, t8 = t & 3;
    s8v v8 = *reinterpret_cast<const s8v*>(&stage[h2 * 40 + t8 * 8]);
    *reinterpret_cast<s8v*>(&vt[(b * 128 + h2) * T_DIM + tbase + t8 * 8]) = v8;
  }
}

// ---------- attn2 staging macro (R17-verified) ----------
#define ATTN_STAGE(KV0, BUF)                                              \
  _Pragma("unroll") for (int j = 0; j < 4; ++j) {                         \
    int row = w * 16 + j * 4 + (lid >> 4);                                \
    int p_ = (row >> 2) & 7;                                              \
    int pg = (p_ & 4) | ((p_ & 1) << 1) | ((p_ >> 1) & 1);                \
    int srow = (row & ~31) | (pg << 2) | (row & 3);                       \
    glds16(kgb + ((KV0) + srow) * 256 + (((lid & 15) ^ (row & 15)) << 4), \
           smem + (BUF) * 65536 + w * 4096 + j * 1024);                   \
  }                                                                       \
  _Pragma("unroll") for (int j = 0; j < 4; ++j) {                         \
    int h = w * 16 + j * 4 + (lid >> 4);                                  \
    glds16(vgb + h * 4096 + (KV0) * 2 + (((lid & 15) ^ (h & 15)) << 4),   \
           smem + (BUF) * 65536 + 32768 + w * 4096 + j * 1024);           \
  }

// ---------- kernel 2a: attn q-64, z=2 (verified R21/22/24 kernel) ----------
__global__ __launch_bounds__(512) void attn2(const ushort* __restrict__ q,
                                             const ushort* __restrict__ k,
                                             const ushort* __restrict__ vt,
                                             float* __restrict__ out,
                                             float* __restrict__ parts,
                                             float* __restrict__ lps) {
  extern __shared__ __align__(16) char smem[];

  const int t   = threadIdx.x;
  const int w   = t >> 6;
  const int lid = t & 63;
  const int hi  = lid >> 5;
  const int ln  = lid & 31;
  const int wq  = w >> 2;
  const int wk  = w & 3;

  const int id = blockIdx.x;
  const int g  = id & 7;
  const int b  = g >> 1;
  const int z  = g & 1;
  const int t0 = (id >> 3) * 64;

  const ushort* qp = q + (b * T_DIM + t0 + wq * 32) * 128;
  b8v aq[8];
#pragma unroll
  for (int s = 0; s < 8; ++s)
    aq[s] = ldb8(&qp[ln * 128 + s * 16 + hi * 8]);

  const char* kgb = (const char*)(k + b * T_DIM * 128);
  const char* vgb = (const char*)(vt + b * 128 * T_DIM);
  const int kv_base = z * 1024;

  const int R = wk * 32 + ln;
  int koff[8];
#pragma unroll
  for (int s = 0; s < 8; ++s)
    koff[s] = R * 256 + (((s * 2 + hi) ^ (R & 15)) << 4);
  int voff[4][2];
#pragma unroll
  for (int ht = 0; ht < 4; ++ht)
#pragma unroll
    for (int s = 0; s < 2; ++s) {
      int Hrow = ht * 32 + ln;
      int chunk = wk * 4 + s * 2 + hi;
      voff[ht][s] = 32768 + Hrow * 256 + ((chunk ^ (Hrow & 15)) << 4);
    }

  f32x16 of[4] = {};
  float lsum = 0.0f;
  const float scale = 0.08838834764831845f;

#define ATTN2_BODY(BUF)                                                  \
  {                                                                      \
    const char* Tb = smem + (BUF) * 65536;                               \
    b8v kfr[8];                                                          \
    _Pragma("unroll") for (int s = 0; s < 8; ++s)                        \
        kfr[s] = ldb8((const ushort*)(Tb + koff[s]));                    \
    f32x16 S = {};                                                       \
    __builtin_amdgcn_s_setprio(1);                                       \
    _Pragma("unroll") for (int s = 0; s < 8; ++s)                        \
        S = mfma32(kfr[s], aq[s], S);                                    \
    __builtin_amdgcn_s_setprio(0);                                       \
    float p[16];                                                         \
    _Pragma("unroll") for (int r = 0; r < 16; ++r) {                     \
      p[r] = __expf(S[r] * scale - 4.0f);                                \
      lsum += p[r];                                                      \
    }                                                                    \
    b8v pk0, pk1;                                                        \
    _Pragma("unroll") for (int r = 0; r < 8; ++r) {                      \
      pk0[r] = (__bf16)p[r];                                             \
      pk1[r] = (__bf16)p[8 + r];                                         \
    }                                                                    \
    __builtin_amdgcn_s_setprio(1);                                       \
    _Pragma("unroll") for (int ht = 0; ht < 4; ++ht) {                   \
      b8v v0 = ldb8((const ushort*)(Tb + voff[ht][0]));                  \
      b8v v1 = ldb8((const ushort*)(Tb + voff[ht][1]));                  \
      of[ht] = mfma32(pk0, v0, of[ht]);                                  \
      of[ht] = mfma32(pk1, v1, of[ht]);                                  \
    }                                                                    \
    __builtin_amdgcn_s_setprio(0);                                       \
  }

  ATTN_STAGE(kv_base, 0)

#pragma unroll 1
  for (int i = 0; i < 8; ++i) {
    BAR_VM(0)
    if (i < 7) { ATTN_STAGE(kv_base + (i + 1) * 128, (i + 1) & 1) }
    ATTN2_BODY(i & 1)
  }
#undef ATTN2_BODY

  lsum += __shfl_xor(lsum, 32);

  __syncthreads();

  float* ob = (float*)smem;            // [3][64][128]
  float* lb = (float*)(smem + 98304);

  if (lid < 32) lb[(wq * 4 + wk) * 32 + lid] = lsum;
  if (wk != 0) {
#pragma unroll
    for (int ht = 0; ht < 4; ++ht)
#pragma unroll
      for (int r = 0; r < 16; ++r) {
        int qm = (r & 3) + 8 * (r >> 2) + 4 * hi;
        ob[((wk - 1) * 64 + wq * 32 + qm) * 128 + ht * 32 + ln] = of[ht][r];
      }
  }
  __syncthreads();
  if (wk == 0) {
    float* dsto = (z == 0) ? out : parts;
#pragma unroll
    for (int ht = 0; ht < 4; ++ht)
#pragma unroll
      for (int r = 0; r < 16; ++r) {
        int qm = (r & 3) + 8 * (r >> 2) + 4 * hi;
        int row = wq * 32 + qm;
        int col = ht * 32 + ln;
        float val = of[ht][r] + ob[(0 * 64 + row) * 128 + col] +
                    ob[(1 * 64 + row) * 128 + col] +
                    ob[(2 * 64 + row) * 128 + col];
        dsto[(b * T_DIM + t0 + row) * 128 + col] = val;
      }
    if (lid < 32) {
      float lt = lb[(wq * 4 + 0) * 32 + lid] + lb[(wq * 4 + 1) * 32 + lid] +
                 lb[(wq * 4 + 2) * 32 + lid] + lb[(wq * 4 + 3) * 32 + lid];
      lps[z * 8192 + b * T_DIM + t0 + wq * 32 + lid] = lt;
    }
  }
}

// ---------- kernel 2b: attn q-64, z=4, kv-64 steps, 2 blocks/CU ----------
// grid (32, 4, 4) x 512 thr; LDS 64 KB (2 x 32 KB buffers) -> 2 blocks/CU
// cross-block overlap of the per-iter drain; total staged bytes unchanged.
// Proven single-BAR_VM(0) loop protocol. Waves = (wq:2) x (wh:2) x (wk:2).
// sigma/swizzle/koff/voff are the attn2-HW-verified formulas at kv-64
// geometry (V rows 128 B). Partials z=1..3 written bf16 to parts16.
__global__ __launch_bounds__(512) void attn3(const ushort* __restrict__ q,
                                             const ushort* __restrict__ k,
                                             const ushort* __restrict__ vt,
                                             float* __restrict__ out,
                                             ushort* __restrict__ parts16,
                                             float* __restrict__ lps) {
  extern __shared__ __align__(16) char smem[];  // 2 x 32 KB

  const int t   = threadIdx.x;
  const int w   = t >> 6;
  const int lid = t & 63;
  const int hi  = lid >> 5;
  const int ln  = lid & 31;
  const int wq  = w >> 2;
  const int wh  = (w >> 1) & 1;
  const int wk  = w & 1;
  const int b   = blockIdx.y;
  const int z   = blockIdx.z;
  const int t0  = blockIdx.x * 64;

  const ushort* qp = q + (b * T_DIM + t0 + wq * 32) * 128;
  b8v aq[8];
#pragma unroll
  for (int s = 0; s < 8; ++s)
    aq[s] = ldb8(&qp[ln * 128 + s * 16 + hi * 8]);

  const char* kgb = (const char*)(k + b * T_DIM * 128);
  const char* vgb = (const char*)(vt + b * 128 * T_DIM);
  const int kv_base = z * 512;

  const int R = wk * 32 + ln;
  int koff[8];
#pragma unroll
  for (int s = 0; s < 8; ++s)
    koff[s] = R * 256 + (((s * 2 + hi) ^ (R & 15)) << 4);
  int voff[2][2];
#pragma unroll
  for (int ht = 0; ht < 2; ++ht)
#pragma unroll
    for (int s = 0; s < 2; ++s) {
      int Hrow = wh * 64 + ht * 32 + ln;
      int chunk = wk * 4 + s * 2 + hi;
      voff[ht][s] = 16384 + Hrow * 128 + ((chunk ^ (Hrow & 7)) << 4);
    }

  f32x16 of[2] = {};
  float lsum = 0.0f;
  const float scale = 0.08838834764831845f;

#define A3_STAGE(KV0, BUF)                                                \
  _Pragma("unroll") for (int j = 0; j < 2; ++j) {                         \
    int row = (w * 2 + j) * 4 + (lid >> 4);                               \
    int p_ = (row >> 2) & 7;                                              \
    int pg = (p_ & 4) | ((p_ & 1) << 1) | ((p_ >> 1) & 1);                \
    int srow = (row & ~31) | (pg << 2) | (row & 3);                       \
    glds16(kgb + ((KV0) + srow) * 256 + (((lid & 15) ^ (row & 15)) << 4), \
           smem + (BUF) * 32768 + (w * 2 + j) * 1024);                    \
  }                                                                       \
  _Pragma("unroll") for (int j = 0; j < 2; ++j) {                         \
    int h = (w * 2 + j) * 8 + (lid >> 3);                                 \
    glds16(vgb + h * 4096 + (KV0) * 2 + (((lid & 7) ^ (h & 7)) << 4),     \
           smem + (BUF) * 32768 + 16384 + (w * 2 + j) * 1024);            \
  }

#define A3_BODY(BUF)                                                     \
  {                                                                      \
    const char* Tb = smem + (BUF) * 32768;                               \
    b8v kfr[8];                                                          \
    _Pragma("unroll") for (int s = 0; s < 8; ++s)                        \
        kfr[s] = ldb8((const ushort*)(Tb + koff[s]));                    \
    f32x16 S = {};                                                       \
    __builtin_amdgcn_s_setprio(1);                                       \
    _Pragma("unroll") for (int s = 0; s < 8; ++s)                        \
        S = mfma32(kfr[s], aq[s], S);                                    \
    __builtin_amdgcn_s_setprio(0);                                       \
    float p[16];                                                         \
    _Pragma("unroll") for (int r = 0; r < 16; ++r) {                     \
      p[r] = __expf(S[r] * scale - 4.0f);                                \
      lsum += p[r];                                                      \
    }                                                                    \
    b8v pk0, pk1;                                                        \
    _Pragma("unroll") for (int r = 0; r < 8; ++r) {                      \
      pk0[r] = (__bf16)p[r];                                             \
      pk1[r] = (__bf16)p[8 + r];                                         \
    }                                                                    \
    __builtin_amdgcn_s_setprio(1);                                       \
    _Pragma("unroll") for (int ht = 0; ht < 2; ++ht) {                   \
      b8v v0 = ldb8((const ushort*)(Tb + voff[ht][0]));                  \
      b8v v1 = ldb8((const ushort*)(Tb + voff[ht][1]));                  \
      of[ht] = mfma32(pk0, v0, of[ht]);                                  \
      of[ht] = mfma32(pk1, v1, of[ht]);                                  \
    }                                                                    \
    __builtin_amdgcn_s_setprio(0);                                       \
  }

  A3_STAGE(kv_base, 0)

#pragma unroll 1
  for (int i = 0; i < 8; ++i) {
    BAR_VM(0)
    if (i < 7) { A3_STAGE(kv_base + (i + 1) * 64, (i + 1) & 1) }
    A3_BODY(i & 1)
  }
#undef A3_STAGE
#undef A3_BODY

  lsum += __shfl_xor(lsum, 32);

  __syncthreads();

  float* ob = (float*)smem;            // [4 (wq,wh)][32 q][64 h] = 32 KB
  float* lb = (float*)(smem + 32768);  // [2 wk][2 wq][32]

  if (wh == 0 && lid < 32) lb[(wk * 2 + wq) * 32 + lid] = lsum;
  if (wk == 1) {
#pragma unroll
    for (int ht = 0; ht < 2; ++ht)
#pragma unroll
      for (int r = 0; r < 16; ++r) {
        int qm = (r & 3) + 8 * (r >> 2) + 4 * hi;
        ob[(wq * 2 + wh) * 2048 + qm * 64 + ht * 32 + ln] = of[ht][r];
      }
  }
  __syncthreads();
  if (wk == 0) {
#pragma unroll
    for (int ht = 0; ht < 2; ++ht)
#pragma unroll
      for (int r = 0; r < 16; ++r) {
        int qm = (r & 3) + 8 * (r >> 2) + 4 * hi;
        int row = wq * 32 + qm;
        int col = wh * 64 + ht * 32 + ln;
        float val =
            of[ht][r] + ob[(wq * 2 + wh) * 2048 + qm * 64 + ht * 32 + ln];
        long idx = (long)(b * T_DIM + t0 + row) * 128 + col;
        if (z == 0)
          out[idx] = val;
        else
          parts16[(long)(z - 1) * 1048576 + idx] = bfu(val);
      }
    if (wh == 0 && lid < 32) {
      float lt = lb[(0 * 2 + wq) * 32 + lid] + lb[(1 * 2 + wq) * 32 + lid];
      lps[z * 8192 + b * T_DIM + t0 + wq * 32 + lid] = lt;
    }
  }
}

// ---------- kernel 3a: merge 2 f32 partial sets ----------
__global__ __launch_bounds__(256) void fin(float* __restrict__ out,
                                           const float* __restrict__ parts,
                                           const float* __restrict__ lps) {
  int tid = blockIdx.x * 256 + threadIdx.x;
  int idx = tid * 4;
  int row = idx >> 7;
  float inv = 1.0f / (lps[row] + lps[8192 + row]);
  f32x4 a = *reinterpret_cast<const f32x4*>(out + idx);
  f32x4 c = *reinterpret_cast<const f32x4*>(parts + idx);
  f32x4 r;
#pragma unroll
  for (int i = 0; i < 4; ++i) r[i] = (a[i] + c[i]) * inv;
  *reinterpret_cast<f32x4*>(out + idx) = r;
}

// ---------- kernel 3b: merge 4 partial sets (z=1..3 bf16) ----------
__global__ __launch_bounds__(256) void fin4(float* __restrict__ out,
                                            const ushort* __restrict__ parts16,
                                            const float* __restrict__ lps) {
  int tid = blockIdx.x * 256 + threadIdx.x;
  int idx = tid * 4;
  int row = idx >> 7;
  float l = lps[row] + lps[8192 + row] + lps[16384 + row] + lps[24576 + row];
  float inv = 1.0f / l;
  f32x4 a = *reinterpret_cast<const f32x4*>(out + idx);
#pragma unroll
  for (int zz = 0; zz < 3; ++zz) {
    s4v u = *reinterpret_cast<const s4v*>(parts16 + (long)zz * 1048576 + idx);
#pragma unroll
    for (int i = 0; i < 4; ++i) a[i] += b2f((ushort)u[i]);
  }
  f32x4 r;
#pragma unroll
  for (int i = 0; i < 4; ++i) r[i] = a[i] * inv;
  *reinterpret_cast<f32x4*>(out + idx) = r;
}

// ---------- launcher ----------
extern "C" void kernel_launch(void* const* d_in, const int* in_sizes, int n_in,
                              void* d_out, int out_size, void* d_ws,
                              size_t ws_size, hipStream_t stream) {
  const float* x  = (const float*)d_in[0];
  const float* Wk = (const float*)d_in[1];
  const float* Wq = (const float*)d_in[2];
  const float* Wv = (const float*)d_in[3];
  float* out = (float*)d_out;

  char* ws = (char*)d_ws;
  const bool big = ws_size >= 13500416u;  // tight layout needs 12.88 MiB

  (void)hipFuncSetAttribute(reinterpret_cast<const void*>(&attn2),
                            hipFuncAttributeMaxDynamicSharedMemorySize, 131072);
  (void)hipFuncSetAttribute(reinterpret_cast<const void*>(&attn3),
                            hipFuncAttributeMaxDynamicSharedMemorySize, 65536);

  if (big) {
    // tight: Wt@0 (0.75M), qb@0.75M, kb@2.75M, vtb@4.75M,
    //        parts16@6.75M (3 x 2M bf16), lps@12.75M (4 x 32K)
    ushort* Wt  = (ushort*)ws;
    ushort* qb  = (ushort*)(ws + 786432);
    ushort* kb  = (ushort*)(ws + 2883584);
    ushort* vtb = (ushort*)(ws + 4980736);
    ushort* parts16 = (ushort*)(ws + 7077888);
    float* lps = (float*)(ws + 13369344);

    wconv<<<dim3(32, 2, 3), dim3(256), 0, stream>>>(Wq, Wk, Wv, Wt);
    proj<<<dim3(256, 3), dim3(512), 0, stream>>>(x, Wt, qb, kb, vtb);
    attn3<<<dim3(32, 4, 4), dim3(512), 65536, stream>>>(qb, kb, vtb, out,
                                                        parts16, lps);
    fin4<<<dim3(1024), dim3(256), 0, stream>>>(out, parts16, lps);
  } else {
    // proven R24 layout/path
    ushort* Wt  = (ushort*)ws;
    ushort* qb  = (ushort*)(ws + (1u << 20));
    ushort* kb  = (ushort*)(ws + 3u * (1u << 20));
    ushort* vtb = (ushort*)(ws + 5u * (1u << 20));
    float* parts = (float*)(ws + 8u * (1u << 20));
    float* lps   = (float*)(ws + 12u * (1u << 20));

    wconv<<<dim3(32, 2, 3), dim3(256), 0, stream>>>(Wq, Wk, Wv, Wt);
    proj<<<dim3(256, 3), dim3(512), 0, stream>>>(x, Wt, qb, kb, vtb);
    attn2<<<dim3(256), dim3(512), 131072, stream>>>(qb, kb, vtb, out,
                                                    parts, lps);
    fin<<<dim3(1024), dim3(256), 0, stream>>>(out, parts, lps);
  }
}

// Round 26
// 47.883 us; speedup vs baseline: 1.1685x; 1.1685x over previous
//
#include <hip/hip_runtime.h>
#include <hip/hip_bf16.h>

typedef float  f32x4  __attribute__((ext_vector_type(4)));
typedef float  f32x8  __attribute__((ext_vector_type(8)));
typedef float  f32x16 __attribute__((ext_vector_type(16)));
typedef short  s4v    __attribute__((ext_vector_type(4)));
typedef short  s8v    __attribute__((ext_vector_type(8)));
typedef __bf16 b4v    __attribute__((ext_vector_type(4)));
typedef __bf16 b8v    __attribute__((ext_vector_type(8)));
typedef unsigned int u32;
typedef unsigned short ushort;

#define T_DIM  2048
#define C_DIM  1024

// ---------- helpers ----------

typedef const __attribute__((address_space(1))) u32 gu32;
typedef __attribute__((address_space(3))) u32 lu32;

static __device__ __forceinline__ void glds16(const void* g, void* l) {
  __builtin_amdgcn_global_load_lds((gu32*)g, (lu32*)l, 16, 0, 0);
}

static __device__ __forceinline__ b8v ldb8(const ushort* p) {
  return __builtin_bit_cast(b8v, *reinterpret_cast<const s8v*>(p));
}

static __device__ __forceinline__ b4v cvt4(f32x4 v) {
  b4v r;
#pragma unroll
  for (int i = 0; i < 4; ++i) r[i] = (__bf16)v[i];
  return r;
}

static __device__ __forceinline__ ushort bfu(float f) {
  __bf16 h = (__bf16)f;
  return __builtin_bit_cast(ushort, h);
}

static __device__ __forceinline__ f32x16 mfma32(b8v a, b8v b, f32x16 c) {
  return __builtin_amdgcn_mfma_f32_32x32x16_bf16(a, b, c, 0, 0, 0);
}

#define BAR_VM(N)                                                        \
  asm volatile("s_waitcnt vmcnt(" #N ") lgkmcnt(0)" ::: "memory");       \
  __builtin_amdgcn_s_barrier();                                          \
  asm volatile("" ::: "memory");

// ---------- kernel 0: W -> Wt bf16 transposed [3][128][1024] ----------
__global__ __launch_bounds__(256) void wconv(const float* __restrict__ Wq,
                                             const float* __restrict__ Wk,
                                             const float* __restrict__ Wv,
                                             ushort* __restrict__ Wt) {
  __shared__ float lds[32][65];
  const int m  = blockIdx.z;
  const int c0 = blockIdx.x * 32;
  const int h0 = blockIdx.y * 64;
  const float* W = (m == 0) ? Wq : (m == 1) ? Wk : Wv;

  const int cl = threadIdx.x >> 3;         // 0..31
  const int h8 = (threadIdx.x & 7) * 8;    // 0..56
  {
    float4 a = *reinterpret_cast<const float4*>(W + (c0 + cl) * 128 + h0 + h8);
    float4 b =
        *reinterpret_cast<const float4*>(W + (c0 + cl) * 128 + h0 + h8 + 4);
    lds[cl][h8] = a.x; lds[cl][h8 + 1] = a.y;
    lds[cl][h8 + 2] = a.z; lds[cl][h8 + 3] = a.w;
    lds[cl][h8 + 4] = b.x; lds[cl][h8 + 5] = b.y;
    lds[cl][h8 + 6] = b.z; lds[cl][h8 + 7] = b.w;
  }
  __syncthreads();
  const int hl = threadIdx.x >> 2;         // 0..63
  const int cs = (threadIdx.x & 3) * 8;    // 0..24
  s8v o;
#pragma unroll
  for (int i = 0; i < 8; ++i) o[i] = (short)bfu(lds[cs + i][hl]);
  *reinterpret_cast<s8v*>(Wt + (m * 128 + h0 + hl) * C_DIM + c0 + cs) = o;
}

// ---------- kernel 1: q/k/v projection, 8-wave K-split, 32x128 tile ----------
// grid (256, 3) x 512 thr (8 waves = ks:2 x nc:4). Wave = 32 rows x 32 cols x
// K-half (32 of the 64 BK). LDS 41 KB (red/stage alias dead Bb) -> 3 blocks/CU
// x 8 waves = 6 waves/SIMD. All read/stage/epilogue formulas = round-20's
// (HW-verified); only the wave indexing and the K-half merge are new.
__global__ __launch_bounds__(512) void proj(const float* __restrict__ x,
                                            const ushort* __restrict__ Wt,
                                            ushort* __restrict__ q,
                                            ushort* __restrict__ k,
                                            ushort* __restrict__ vt) {
  __shared__ __align__(16) ushort Ab[2][32 * 72];   // 9216 B
  __shared__ __align__(16) ushort Bb[2][128 * 64];  // 32768 B
  float* red = (float*)&Bb[0][0];                   // 16 KB alias (post-loop)
  ushort* stage = &Bb[1][0];                        // 16 KB alias (post-loop)

  const int t   = threadIdx.x;
  const int w   = t >> 6;        // 0..7
  const int lid = t & 63;
  const int hi  = lid >> 5;
  const int ln  = lid & 31;
  const int ks  = w >> 2;        // K-half
  const int nc  = w & 3;         // col tile
  const int m   = blockIdx.y;
  const int r0  = blockIdx.x * 32;

  const int arow = t >> 4;          // 0..31
  const int acol = (t & 15) * 4;    // 0..60
  const float* ag = x + (r0 + arow) * C_DIM + acol;

  const int bswz = (((lid & 7) ^ (lid >> 3)) << 4);
  const char* bg = (const char*)(Wt + m * 128 * C_DIM);

  f32x16 acc[2] = {};

#define PROJ_BSTAGE(KK, BUF)                                              \
  _Pragma("unroll") for (int j = 0; j < 2; ++j) {                         \
    int h = j * 64 + w * 8 + (lid >> 3);                                  \
    glds16(bg + h * 2048 + (KK) * 2 + bswz,                               \
           (char*)&Bb[BUF][0] + j * 8192 + w * 1024);                     \
  }

  // ---- prologue ----
  f32x4 av = *reinterpret_cast<const f32x4*>(ag);
  PROJ_BSTAGE(0, 0)
  {
    b4v ac = cvt4(av);
    *reinterpret_cast<s4v*>(&Ab[0][arow * 72 + acol]) =
        __builtin_bit_cast(s4v, ac);
  }
  __syncthreads();

  int cur = 0;
#pragma unroll 1
  for (int i = 0; i < 16; ++i) {
    const int nxt = cur ^ 1;
    f32x4 an;
    if (i < 15) {
      const int kk = (i + 1) * 64;
      PROJ_BSTAGE(kk, nxt)
      an = *reinterpret_cast<const f32x4*>(ag + kk);
    }

    // ---- compute on cur: this wave's K-half (2 mfma32) ----
    const int h = nc * 32 + ln;
#pragma unroll
    for (int c = 0; c < 2; ++c) {
      const int s = ks * 2 + c;
      b8v af = ldb8(&Ab[cur][ln * 72 + s * 16 + hi * 8]);
      int inner = ((s * 2 + hi) << 4) ^ ((h & 7) << 4);
      b8v bf =
          ldb8((const ushort*)((const char*)&Bb[cur][0] + h * 128 + inner));
      __builtin_amdgcn_s_setprio(1);
      acc[c] = mfma32(af, bf, acc[c]);
      __builtin_amdgcn_s_setprio(0);
    }

    if (i < 15) {
      b4v anc = cvt4(an);
      *reinterpret_cast<s4v*>(&Ab[nxt][arow * 72 + acol]) =
          __builtin_bit_cast(s4v, anc);
    }
    __syncthreads();
    cur = nxt;
  }
#undef PROJ_BSTAGE

  f32x16 fa = acc[0] + acc[1];

  // ---- merge the two K-halves (red aliases dead Bb[0]) ----
  if (ks == 1) {
#pragma unroll
    for (int r = 0; r < 16; ++r) {
      int qm = (r & 3) + 8 * (r >> 2) + 4 * hi;
      red[(nc * 32 + qm) * 32 + ln] = fa[r];
    }
  }
  __syncthreads();
  if (ks == 0) {
#pragma unroll
    for (int r = 0; r < 16; ++r) {
      int qm = (r & 3) + 8 * (r >> 2) + 4 * hi;
      fa[r] += red[(nc * 32 + qm) * 32 + ln];
    }
    // ---- write to stage (aliases dead Bb[1]) ----
    if (m < 2) {
#pragma unroll
      for (int r = 0; r < 16; ++r) {
        int row = (r & 3) + 8 * (r >> 2) + 4 * hi;
        stage[row * 136 + nc * 32 + ln] = bfu(fa[r]);
      }
    } else {
#pragma unroll
      for (int r = 0; r < 16; ++r) {
        int trow = (r & 3) + 8 * (r >> 2) + 4 * hi;
        stage[(nc * 32 + ln) * 40 + trow] = bfu(fa[r]);
      }
    }
  }
  __syncthreads();

  // ---- coalesced copy to global (512 threads, single pass) ----
  if (m < 2) {
    ushort* dst = (m == 0) ? q : k;
    int row = t >> 4, col8 = t & 15;  // 32 rows x 16 chunks of 8
    s8v v8 = *reinterpret_cast<const s8v*>(&stage[row * 136 + col8 * 8]);
    *reinterpret_cast<s8v*>(&dst[(r0 + row) * 128 + col8 * 8]) = v8;
  } else {
    int b = blockIdx.x >> 6;
    int tbase = (blockIdx.x & 63) * 32;
    int h2 = t >> 2, t8 = t & 3;  // 128 h x 4 chunks of 8
    s8v v8 = *reinterpret_cast<const s8v*>(&stage[h2 * 40 + t8 * 8]);
    *reinterpret_cast<s8v*>(&vt[(b * 128 + h2) * T_DIM + tbase + t8 * 8]) = v8;
  }
}

// ---------- attn staging macro (R17-verified) ----------
#define ATTN_STAGE(KV0, BUF)                                              \
  _Pragma("unroll") for (int j = 0; j < 4; ++j) {                         \
    int row = w * 16 + j * 4 + (lid >> 4);                                \
    int p_ = (row >> 2) & 7;                                              \
    int pg = (p_ & 4) | ((p_ & 1) << 1) | ((p_ >> 1) & 1);                \
    int srow = (row & ~31) | (pg << 2) | (row & 3);                       \
    glds16(kgb + ((KV0) + srow) * 256 + (((lid & 15) ^ (row & 15)) << 4), \
           smem + (BUF) * 65536 + w * 4096 + j * 1024);                   \
  }                                                                       \
  _Pragma("unroll") for (int j = 0; j < 4; ++j) {                         \
    int h = w * 16 + j * 4 + (lid >> 4);                                  \
    glds16(vgb + h * 4096 + (KV0) * 2 + (((lid & 15) ^ (h & 15)) << 4),   \
           smem + (BUF) * 65536 + 32768 + w * 4096 + j * 1024);           \
  }

// ---------- kernel 2: attn q-64, z=2, XCD-grouped dispatch ----------
// (verified round-21/22/24 kernel: single BAR_VM(0) per iter — measured
// optimum of this family across all wait/granularity variants tested)
__global__ __launch_bounds__(512) void attn2(const ushort* __restrict__ q,
                                             const ushort* __restrict__ k,
                                             const ushort* __restrict__ vt,
                                             float* __restrict__ out,
                                             float* __restrict__ parts,
                                             float* __restrict__ lps) {
  extern __shared__ __align__(16) char smem[];

  const int t   = threadIdx.x;
  const int w   = t >> 6;
  const int lid = t & 63;
  const int hi  = lid >> 5;
  const int ln  = lid & 31;
  const int wq  = w >> 2;
  const int wk  = w & 3;

  const int id = blockIdx.x;
  const int g  = id & 7;
  const int b  = g >> 1;
  const int z  = g & 1;
  const int t0 = (id >> 3) * 64;

  const ushort* qp = q + (b * T_DIM + t0 + wq * 32) * 128;
  b8v aq[8];
#pragma unroll
  for (int s = 0; s < 8; ++s)
    aq[s] = ldb8(&qp[ln * 128 + s * 16 + hi * 8]);

  const char* kgb = (const char*)(k + b * T_DIM * 128);
  const char* vgb = (const char*)(vt + b * 128 * T_DIM);
  const int kv_base = z * 1024;

  const int R = wk * 32 + ln;
  int koff[8];
#pragma unroll
  for (int s = 0; s < 8; ++s)
    koff[s] = R * 256 + (((s * 2 + hi) ^ (R & 15)) << 4);
  int voff[4][2];
#pragma unroll
  for (int ht = 0; ht < 4; ++ht)
#pragma unroll
    for (int s = 0; s < 2; ++s) {
      int Hrow = ht * 32 + ln;
      int chunk = wk * 4 + s * 2 + hi;
      voff[ht][s] = 32768 + Hrow * 256 + ((chunk ^ (Hrow & 15)) << 4);
    }

  f32x16 of[4] = {};
  float lsum = 0.0f;
  const float scale = 0.08838834764831845f;

#define ATTN2_BODY(BUF)                                                  \
  {                                                                      \
    const char* Tb = smem + (BUF) * 65536;                               \
    b8v kfr[8];                                                          \
    _Pragma("unroll") for (int s = 0; s < 8; ++s)                        \
        kfr[s] = ldb8((const ushort*)(Tb + koff[s]));                    \
    f32x16 S = {};                                                       \
    __builtin_amdgcn_s_setprio(1);                                       \
    _Pragma("unroll") for (int s = 0; s < 8; ++s)                        \
        S = mfma32(kfr[s], aq[s], S);                                    \
    __builtin_amdgcn_s_setprio(0);                                       \
    float p[16];                                                         \
    _Pragma("unroll") for (int r = 0; r < 16; ++r) {                     \
      p[r] = __expf(S[r] * scale - 4.0f);                                \
      lsum += p[r];                                                      \
    }                                                                    \
    b8v pk0, pk1;                                                        \
    _Pragma("unroll") for (int r = 0; r < 8; ++r) {                      \
      pk0[r] = (__bf16)p[r];                                             \
      pk1[r] = (__bf16)p[8 + r];                                         \
    }                                                                    \
    __builtin_amdgcn_s_setprio(1);                                       \
    _Pragma("unroll") for (int ht = 0; ht < 4; ++ht) {                   \
      b8v v0 = ldb8((const ushort*)(Tb + voff[ht][0]));                  \
      b8v v1 = ldb8((const ushort*)(Tb + voff[ht][1]));                  \
      of[ht] = mfma32(pk0, v0, of[ht]);                                  \
      of[ht] = mfma32(pk1, v1, of[ht]);                                  \
    }                                                                    \
    __builtin_amdgcn_s_setprio(0);                                       \
  }

  ATTN_STAGE(kv_base, 0)

#pragma unroll 1
  for (int i = 0; i < 8; ++i) {
    BAR_VM(0)
    if (i < 7) { ATTN_STAGE(kv_base + (i + 1) * 128, (i + 1) & 1) }
    ATTN2_BODY(i & 1)
  }
#undef ATTN2_BODY

  lsum += __shfl_xor(lsum, 32);

  __syncthreads();

  float* ob = (float*)smem;            // [3][64][128]
  float* lb = (float*)(smem + 98304);

  if (lid < 32) lb[(wq * 4 + wk) * 32 + lid] = lsum;
  if (wk != 0) {
#pragma unroll
    for (int ht = 0; ht < 4; ++ht)
#pragma unroll
      for (int r = 0; r < 16; ++r) {
        int qm = (r & 3) + 8 * (r >> 2) + 4 * hi;
        ob[((wk - 1) * 64 + wq * 32 + qm) * 128 + ht * 32 + ln] = of[ht][r];
      }
  }
  __syncthreads();
  if (wk == 0) {
    float* dsto = (z == 0) ? out : parts;
#pragma unroll
    for (int ht = 0; ht < 4; ++ht)
#pragma unroll
      for (int r = 0; r < 16; ++r) {
        int qm = (r & 3) + 8 * (r >> 2) + 4 * hi;
        int row = wq * 32 + qm;
        int col = ht * 32 + ln;
        float val = of[ht][r] + ob[(0 * 64 + row) * 128 + col] +
                    ob[(1 * 64 + row) * 128 + col] +
                    ob[(2 * 64 + row) * 128 + col];
        dsto[(b * T_DIM + t0 + row) * 128 + col] = val;
      }
    if (lid < 32) {
      float lt = lb[(wq * 4 + 0) * 32 + lid] + lb[(wq * 4 + 1) * 32 + lid] +
                 lb[(wq * 4 + 2) * 32 + lid] + lb[(wq * 4 + 3) * 32 + lid];
      lps[z * 8192 + b * T_DIM + t0 + wq * 32 + lid] = lt;
    }
  }
}

// ---------- kernel 3: merge the two kv-halves ----------
__global__ __launch_bounds__(256) void fin(float* __restrict__ out,
                                           const float* __restrict__ parts,
                                           const float* __restrict__ lps) {
  int tid = blockIdx.x * 256 + threadIdx.x;
  int idx = tid * 4;
  int row = idx >> 7;
  float inv = 1.0f / (lps[row] + lps[8192 + row]);
  f32x4 a = *reinterpret_cast<const f32x4*>(out + idx);
  f32x4 c = *reinterpret_cast<const f32x4*>(parts + idx);
  f32x4 r;
#pragma unroll
  for (int i = 0; i < 4; ++i) r[i] = (a[i] + c[i]) * inv;
  *reinterpret_cast<f32x4*>(out + idx) = r;
}

// ---------- launcher ----------
extern "C" void kernel_launch(void* const* d_in, const int* in_sizes, int n_in,
                              void* d_out, int out_size, void* d_ws,
                              size_t ws_size, hipStream_t stream) {
  const float* x  = (const float*)d_in[0];
  const float* Wk = (const float*)d_in[1];
  const float* Wq = (const float*)d_in[2];
  const float* Wv = (const float*)d_in[3];
  float* out = (float*)d_out;

  char* ws = (char*)d_ws;
  ushort* Wt  = (ushort*)ws;                        // 0.75 MB
  ushort* qb  = (ushort*)(ws + (1u << 20));         // 2 MB
  ushort* kb  = (ushort*)(ws + 3u * (1u << 20));    // 2 MB
  ushort* vtb = (ushort*)(ws + 5u * (1u << 20));    // 2 MB
  float* parts = (float*)(ws + 8u * (1u << 20));    // 4 MB
  float* lps   = (float*)(ws + 12u * (1u << 20));   // 2 x 32 KB

  (void)hipFuncSetAttribute(reinterpret_cast<const void*>(&attn2),
                            hipFuncAttributeMaxDynamicSharedMemorySize, 131072);

  wconv<<<dim3(32, 2, 3), dim3(256), 0, stream>>>(Wq, Wk, Wv, Wt);
  proj<<<dim3(256, 3), dim3(512), 0, stream>>>(x, Wt, qb, kb, vtb);
  attn2<<<dim3(256), dim3(512), 131072, stream>>>(qb, kb, vtb, out,
                                                  parts, lps);
  fin<<<dim3(1024), dim3(256), 0, stream>>>(out, parts, lps);
}